// Round 15
// baseline (830.904 us; speedup 1.0000x reference)
//
#include <hip/hip_runtime.h>
#include <stdint.h>

constexpr int NB = 32, NS = 64, NT = 64, NV = 32000, NE = 256, NH = 512;
constexpr int RG = 64;          // recurrence wgs: 2 batch-groups x 32 unit-groups
constexpr int UW = 16;          // units per wg
constexpr int BW = 16;          // batches per wg
constexpr int GRW = 3 * UW;     // 48 gate rows per wg
constexpr int TSTEPS = NS + NT - 1;   // 127
constexpr int NWK = 192;        // fc worker wgs: 12 per m-group x 16 groups

typedef unsigned short u16;
typedef unsigned u32;
typedef short bf16x8 __attribute__((ext_vector_type(8)));
typedef float f32x4  __attribute__((ext_vector_type(4)));
typedef unsigned u32x4 __attribute__((ext_vector_type(4)));

__device__ inline u16 f2bf(float f){
  unsigned int u = __float_as_uint(f);
  u = u + 0x7FFFu + ((u >> 16) & 1u);
  return (u16)(u >> 16);
}
__device__ inline float bf2f(u16 h){ return __uint_as_float(((unsigned)h) << 16); }

__device__ inline void gload_lds16(const u16* g, u16* l){
  __builtin_amdgcn_global_load_lds((const __attribute__((address_space(1))) void*)g,
                                   (__attribute__((address_space(3))) void*)l, 16, 0, 0);
}

// W plane: 48 rows x 512 bf16. 16B chunk (r<48, k16<64):
__device__ inline int ldsW_off(int r, int k16){
  return (k16 >> 2) * 3072 + ((r >> 4) << 10) + (((((k16 & 3) << 4)) | (r & 15)) << 4);
}
// h plane: 16 rows x 512 bf16, XOR-swizzled (r10-verified 0-conflict)
__device__ inline int ldsH_off(int r, int k16){
  int base = ((k16 >> 2) << 10) + (((((k16 & 3) << 4)) | r) << 4);
  return base ^ (((base >> 10) & 15) << 4);
}

// 8 x 16B coherent loads (bypass L1/L2, read MALL), waitcnt INSIDE the asm block.
__device__ inline void load_h128(const u32* p, u32x4 v[8]){
  asm volatile(
    "global_load_dwordx4 %0, %8, off sc0 sc1\n\t"
    "global_load_dwordx4 %1, %8, off offset:16 sc0 sc1\n\t"
    "global_load_dwordx4 %2, %8, off offset:32 sc0 sc1\n\t"
    "global_load_dwordx4 %3, %8, off offset:48 sc0 sc1\n\t"
    "global_load_dwordx4 %4, %8, off offset:64 sc0 sc1\n\t"
    "global_load_dwordx4 %5, %8, off offset:80 sc0 sc1\n\t"
    "global_load_dwordx4 %6, %8, off offset:96 sc0 sc1\n\t"
    "global_load_dwordx4 %7, %8, off offset:112 sc0 sc1\n\t"
    "s_waitcnt vmcnt(0)"
    : "=&v"(v[0]), "=&v"(v[1]), "=&v"(v[2]), "=&v"(v[3]),
      "=&v"(v[4]), "=&v"(v[5]), "=&v"(v[6]), "=&v"(v[7])
    : "v"(p)
    : "memory");
}

// 8 producer-block loads (2 bases, 1KB-strided imm offsets), waitcnt INSIDE.
__device__ inline void load8blk(const u32* p0, const u32* p1, u32x4 v[8]){
  asm volatile(
    "global_load_dwordx4 %0, %8, off sc0 sc1\n\t"
    "global_load_dwordx4 %1, %8, off offset:1024 sc0 sc1\n\t"
    "global_load_dwordx4 %2, %8, off offset:2048 sc0 sc1\n\t"
    "global_load_dwordx4 %3, %8, off offset:3072 sc0 sc1\n\t"
    "global_load_dwordx4 %4, %9, off sc0 sc1\n\t"
    "global_load_dwordx4 %5, %9, off offset:1024 sc0 sc1\n\t"
    "global_load_dwordx4 %6, %9, off offset:2048 sc0 sc1\n\t"
    "global_load_dwordx4 %7, %9, off offset:3072 sc0 sc1\n\t"
    "s_waitcnt vmcnt(0)"
    : "=&v"(v[0]), "=&v"(v[1]), "=&v"(v[2]), "=&v"(v[3]),
      "=&v"(v[4]), "=&v"(v[5]), "=&v"(v[6]), "=&v"(v[7])
    : "v"(p0), "v"(p1)
    : "memory");
}

// ---------------------------------------------------------------- zero init
__global__ void zero_init(float* __restrict__ out, u16* __restrict__ xdecpad, u32* __restrict__ hcpad,
                          u32* __restrict__ Hpk, u32* __restrict__ flags){
  int i = blockIdx.x * blockDim.x + threadIdx.x, st = gridDim.x * blockDim.x;
  for (int idx = i; idx < NB * NV; idx += st){
    int b = idx / NV, v = idx - b * NV;
    out[(size_t)b * NT * NV + v] = 0.f;
  }
  for (int idx = i; idx < 32 * NE; idx += st) xdecpad[idx] = 0;
  for (int idx = i; idx < 32 * NH; idx += st) hcpad[idx] = 0;     // HallC pad rows 2016..2047
  for (int idx = i; idx < 2 * 2 * 32 * 256; idx += st) Hpk[idx] = 0;  // slot0 = h(0) = 0
  for (int idx = i; idx < 1024; idx += st) flags[idx] = 0;
}

// ---------------------------------------------------------------- f32 -> bf16
__global__ void cvt_f32_bf16(const float* __restrict__ in, u16* __restrict__ out, int n4){
  int i = blockIdx.x * blockDim.x + threadIdx.x, st = gridDim.x * blockDim.x;
  for (int idx = i; idx < n4; idx += st){
    float4 v = ((const float4*)in)[idx];
    unsigned lo = (unsigned)f2bf(v.x) | ((unsigned)f2bf(v.y) << 16);
    unsigned hi = (unsigned)f2bf(v.z) | ((unsigned)f2bf(v.w) << 16);
    *(uint2*)(out + (size_t)idx * 4) = make_uint2(lo, hi);
  }
}

// ---------------------------------------------------------------- f32 -> (bf16 hi, bf16 lo)
__global__ void cvt_hilo(const float* __restrict__ in, u16* __restrict__ hi, u16* __restrict__ lo, int n){
  int i = blockIdx.x * blockDim.x + threadIdx.x, st = gridDim.x * blockDim.x;
  for (int idx = i; idx < n; idx += st){
    float w = in[idx];
    u16 h = f2bf(w);
    hi[idx] = h;
    lo[idx] = f2bf(w - bf2f(h));
  }
}

// ---------------------------------------------------------------- embedding gather (rows m = t*NB + b)
__global__ void embed_k(const int* __restrict__ idx, int ld, int tcount,
                        const float* __restrict__ emb, u16* __restrict__ xbf){
  int tid = blockIdx.x * blockDim.x + threadIdx.x;
  int n4 = tcount * NB * (NE / 4);
  if (tid >= n4) return;
  int e4 = tid & (NE/4 - 1);
  int m  = tid >> 6;
  int t = m / NB, b = m % NB;
  int row = idx[b * ld + t];
  float4 v = ((const float4*)(emb + (size_t)row * NE))[e4];
  unsigned lo = (unsigned)f2bf(v.x) | ((unsigned)f2bf(v.y) << 16);
  unsigned hi = (unsigned)f2bf(v.z) | ((unsigned)f2bf(v.w) << 16);
  *(uint2*)(xbf + (size_t)m * NE + e4 * 4) = make_uint2(lo, hi);
}

// ---------------------------------------------------------------- bf16 MFMA GEMM (gi): C = A*B^T + bias, plain store
template<int KDIM>
__global__ __launch_bounds__(256) void gemm_bt(const u16* __restrict__ A,
                                               const u16* __restrict__ Bm,
                                               const float* __restrict__ bias,
                                               float* __restrict__ C, int Nld)
{
  __shared__ u16 As[2 * 128 * 32];
  __shared__ u16 Bs[2 * 128 * 32];
  const int id = blockIdx.x;
  const int q = gridDim.x >> 3;
  const int wg = (id & 7) * q + (id >> 3);
  const int m0 = (wg & 15) * 128, n0 = (wg >> 4) * 128;
  const int tid  = threadIdx.x;
  const int lane = tid & 63;
  const int w = tid >> 6, wm = w >> 1, wn = w & 1;
  f32x4 acc[4][4] = {};

  const int sr = w * 16 + (lane >> 2);
  const int sc = (lane & 3) * 8;
  const u16* aS = A  + (size_t)(m0 + sr) * KDIM + sc;
  const u16* bS = Bm + (size_t)(n0 + sr) * KDIM + sc;
  u16* asl = As + w * 16 * 32;
  u16* bsl = Bs + w * 16 * 32;

  auto STAGE = [&](int p, int k0){
    u16* ad = asl + p * 4096;
    u16* bd = bsl + p * 4096;
    gload_lds16(aS + k0, ad);
    gload_lds16(aS + (size_t)64 * KDIM + k0, ad + 64 * 32);
    gload_lds16(bS + k0, bd);
    gload_lds16(bS + (size_t)64 * KDIM + k0, bd + 64 * 32);
  };

  constexpr int NK = KDIM / 32;
  STAGE(0, 0);
  __syncthreads();
  for (int t2 = 0; t2 < NK; ++t2){
    if (t2 + 1 < NK) STAGE((t2 + 1) & 1, (t2 + 1) * 32);
    const char* Ab = (const char*)As + (t2 & 1) * 8192;
    const char* Bb = (const char*)Bs + (t2 & 1) * 8192;
    bf16x8 af[4], bfr[4];
    #pragma unroll
    for (int i = 0; i < 4; ++i)
      af[i] = *(const bf16x8*)(Ab + (wm*64 + i*16 + (lane & 15)) * 64 + (lane >> 4) * 16);
    #pragma unroll
    for (int j = 0; j < 4; ++j)
      bfr[j] = *(const bf16x8*)(Bb + (wn*64 + j*16 + (lane & 15)) * 64 + (lane >> 4) * 16);
    #pragma unroll
    for (int i = 0; i < 4; ++i)
      #pragma unroll
      for (int j = 0; j < 4; ++j)
        acc[i][j] = __builtin_amdgcn_mfma_f32_16x16x32_bf16(af[i], bfr[j], acc[i][j], 0, 0, 0);
    __syncthreads();
  }

  #pragma unroll
  for (int i = 0; i < 4; ++i){
    #pragma unroll
    for (int j = 0; j < 4; ++j){
      int col = n0 + wn*64 + j*16 + (lane & 15);
      float bv = bias[col];
      #pragma unroll
      for (int rr = 0; rr < 4; ++rr){
        int row = m0 + wm*64 + i*16 + (lane >> 4) * 4 + rr;
        C[(size_t)row * Nld + col] = acc[i][j][rr] + bv;
      }
    }
  }
}

// ---------------------------------------------------------------- fused persistent kernel
// blocks 0..63: GRU recurrence. Fine-grained per-wave 8-producer pull (r11), loads in
// ONE asm block with waitcnt inside. NEW: explicit per-thread s_waitcnt vmcnt(0) after
// the gate-phase agent stores — __syncthreads is only workgroup-scope and need not
// drain relaxed AGENT stores, so without this the flag could land at MALL before the
// h data (the r11-r14 nondeterminism). blocks 64..255: fc workers (r13 structure).
__global__ __launch_bounds__(256) void gru_fused(
    const u16* __restrict__ WhiE, const u16* __restrict__ WloE,
    const u16* __restrict__ WhiD, const u16* __restrict__ WloD,
    const float* __restrict__ bhhE, const float* __restrict__ bhhD,
    const float* __restrict__ gie, const float* __restrict__ gid,  // [t][b][1536]
    u32* __restrict__ Hpk,            // [2][2][32][16][16] u32
    u32* __restrict__ flags,          // [64] stride 4
    u32* __restrict__ HallC,          // [2048][512] u32 = bf16 hi (agent-published)
    const u16* __restrict__ fcWbf, const float* __restrict__ fc_b,
    float* __restrict__ out)
{
  extern __shared__ char smem[];
  const int tid  = threadIdx.x;
  const int lane = tid & 63;
  const int w    = tid >> 6;

  if (blockIdx.x < RG){
    // ================= recurrence =================
    u16* Whi = (u16*)smem;                    // [48][512] subtiled
    u16* Wlo = Whi + GRW * NH;
    u16* Hhi = Wlo + GRW * NH;                // [16][512] subtiled+swizzled
    u16* Hlo = Hhi + BW * NH;
    float* GH = (float*)(Hlo + BW * NH);      // [48][17]

    const int bg   = blockIdx.x >> 5;
    const int ug   = blockIdx.x & 31;
    const int j0   = ug * UW;
    const int b0   = bg * BW;
    const unsigned myid = blockIdx.x;

    const int gu = tid & 15, gb2 = tid >> 4;
    const int jg = j0 + gu;
    const int bglob = b0 + gb2;
    const float beR = bhhE[jg], beZ = bhhE[NH + jg], beN = bhhE[2*NH + jg];
    const float bdR = bhhD[jg], bdZ = bhhD[NH + jg], bdN = bhhD[2*NH + jg];

    auto stageW = [&](const u16* Hi, const u16* Lo){
      for (int c = tid; c < GRW * 64; c += 256){
        int r = c >> 6, k16 = c & 63;
        int grow = (r >> 4) * NH + j0 + (r & 15);
        int d = ldsW_off(r, k16);
        *(uint4*)((char*)Whi + d) = *(const uint4*)(Hi + (size_t)grow * NH + k16 * 8);
        *(uint4*)((char*)Wlo + d) = *(const uint4*)(Lo + (size_t)grow * NH + k16 * 8);
      }
    };
    stageW(WhiE, WloE);

    for (int t = 0; t < TSTEPS; ++t){
      const bool dec = (t >= NS);
      __syncthreads();                   // all waves past gate (stores already drained below)
      if (tid == 0 && t > 0)
        __hip_atomic_store(&flags[myid * 4], (u32)t, __ATOMIC_RELAXED, __HIP_MEMORY_SCOPE_AGENT);
      if (t == NS) stageW(WhiD, WloD);

      // ---- pull: wave w waits for its 8 producers, then one-shot 8-block load
      {
        const u32* Hq = Hpk + (size_t)((t & 1) * 2 + bg) * 8192;
        const int fb = (bg << 5) + (w << 3);
        int spins = 0;
        while (true){
          u32 f = __hip_atomic_load(&flags[(fb + (lane & 7)) * 4], __ATOMIC_RELAXED, __HIP_MEMORY_SCOPE_AGENT);
          if (__all((int)((lane >= 8) || (w * 8 + lane == ug) || f >= (u32)t))) break;
          __builtin_amdgcn_s_sleep(1);
          if (++spins > (1 << 18)) break;   // failsafe: wrong answer, not hang
        }
        u32x4 v[8];
        const u32* p0 = Hq + ((w * 8 + 0) << 8) + lane * 4;
        const u32* p1 = Hq + ((w * 8 + 4) << 8) + lane * 4;
        load8blk(p0, p1, v);
        __builtin_amdgcn_sched_barrier(0);
        const int prow = lane >> 2, pq = lane & 3;
        #pragma unroll
        for (int p = 0; p < 8; ++p){
          u32 a0 = v[p][0], a1 = v[p][1], a2 = v[p][2], a3 = v[p][3];
          uint2 hw = make_uint2((a0 & 0xffffu) | (a1 << 16), (a2 & 0xffffu) | (a3 << 16));
          uint2 lw = make_uint2((a0 >> 16) | (a1 & 0xffff0000u), (a2 >> 16) | (a3 & 0xffff0000u));
          int k16 = (w * 8 + p) * 2 + (pq >> 1);
          int d = ldsH_off(prow, k16) + (pq & 1) * 8;
          *(uint2*)((char*)Hhi + d) = hw;
          *(uint2*)((char*)Hlo + d) = lw;
        }
      }
      __syncthreads();

      const float* gp = (dec ? (gid + ((size_t)(t - NS) * NB + bglob) * 1536)
                             : (gie + ((size_t)t * NB + bglob) * 1536));
      float gr = gp[jg], gz = gp[NH + jg], gn = gp[2 * NH + jg];

      if (w < 3){
        f32x4 acc0 = {0.f,0.f,0.f,0.f}, acc1 = {0.f,0.f,0.f,0.f};
        const int ab = w * 1024 + lane * 16;
        const int bb = lane * 16;
        #pragma unroll
        for (int kk = 0; kk < 16; kk += 2){
          const int bx0 = kk * 1024 + (bb ^ ((kk & 15) << 4));
          const int bx1 = (kk+1) * 1024 + (bb ^ (((kk+1) & 15) << 4));
          bf16x8 ah0 = *(const bf16x8*)((const char*)Whi + kk * 3072 + ab);
          bf16x8 al0 = *(const bf16x8*)((const char*)Wlo + kk * 3072 + ab);
          bf16x8 bh0 = *(const bf16x8*)((const char*)Hhi + bx0);
          bf16x8 bl0 = *(const bf16x8*)((const char*)Hlo + bx0);
          acc0 = __builtin_amdgcn_mfma_f32_16x16x32_bf16(ah0, bh0, acc0, 0, 0, 0);
          acc0 = __builtin_amdgcn_mfma_f32_16x16x32_bf16(al0, bh0, acc0, 0, 0, 0);
          acc0 = __builtin_amdgcn_mfma_f32_16x16x32_bf16(ah0, bl0, acc0, 0, 0, 0);
          bf16x8 ah1 = *(const bf16x8*)((const char*)Whi + (kk+1) * 3072 + ab);
          bf16x8 al1 = *(const bf16x8*)((const char*)Wlo + (kk+1) * 3072 + ab);
          bf16x8 bh1 = *(const bf16x8*)((const char*)Hhi + bx1);
          bf16x8 bl1 = *(const bf16x8*)((const char*)Hlo + bx1);
          acc1 = __builtin_amdgcn_mfma_f32_16x16x32_bf16(ah1, bh1, acc1, 0, 0, 0);
          acc1 = __builtin_amdgcn_mfma_f32_16x16x32_bf16(al1, bh1, acc1, 0, 0, 0);
          acc1 = __builtin_amdgcn_mfma_f32_16x16x32_bf16(ah1, bl1, acc1, 0, 0, 0);
        }
        f32x4 accs = acc0 + acc1;
        int col = lane & 15;
        #pragma unroll
        for (int r2 = 0; r2 < 4; ++r2){
          int row = w * 16 + ((lane >> 4) << 2) + r2;
          GH[row * 17 + col] = accs[r2];
        }
      }
      __syncthreads();

      {
        float ghr = GH[(0 * UW + gu) * 17 + gb2] + (dec ? bdR : beR);
        float ghz = GH[(1 * UW + gu) * 17 + gb2] + (dec ? bdZ : beZ);
        float ghn = GH[(2 * UW + gu) * 17 + gb2] + (dec ? bdN : beN);
        float r = 1.f / (1.f + expf(-(gr + ghr)));
        float z = 1.f / (1.f + expf(-(gz + ghz)));
        float n = tanhf(gn + r * ghn);
        int coff = ldsH_off(gb2, jg >> 3) + (jg & 7) * 2;
        float hp = bf2f(*(const u16*)((char*)Hhi + coff))
                 + bf2f(*(const u16*)((char*)Hlo + coff));
        float hnew = (1.f - z) * n + z * hp;
        u16 hi = f2bf(hnew);
        u16 lo = f2bf(hnew - bf2f(hi));
        if (dec)
          __hip_atomic_store(&HallC[((size_t)(t - NS) * NB + bglob) * NH + jg], (u32)hi,
                             __ATOMIC_RELAXED, __HIP_MEMORY_SCOPE_AGENT);
        if (t < TSTEPS - 1){
          u32* dst = Hpk + (size_t)((((t + 1) & 1) * 2 + bg) * 32 + ug) * 256 + gb2 * 16 + gu;
          __hip_atomic_store(dst, (u32)hi | ((u32)lo << 16),
                             __ATOMIC_RELAXED, __HIP_MEMORY_SCOPE_AGENT);
        }
        // CRITICAL: drain h/HallC stores to the coherence point in EVERY thread
        // before the barrier that precedes the flag publish. __syncthreads alone
        // (workgroup scope) does not order relaxed AGENT stores.
        asm volatile("s_waitcnt vmcnt(0)" ::: "memory");
      }
    }
    // end flag: last iteration's stores drained by the in-loop explicit waitcnt
    __syncthreads();
    if (tid == 0)
      __hip_atomic_store(&flags[myid * 4], 127u, __ATOMIC_RELAXED, __HIP_MEMORY_SCOPE_AGENT);

  } else {
    // ================= fc worker =================
    u16* Asm = (u16*)smem;                    // [128][512] bf16, row-XOR swizzled (128 KB)
    u16* Bs  = (u16*)(smem + 131072);         // 2 x [128][32] bf16 (16 KB)

    const int wk = blockIdx.x - RG;
    const int g  = wk / 12;
    const int wi = wk - g * 12;
    const u32 need = (g == 15) ? 127u : (u32)(NS + 4 * (g + 1));

    if (w == 0){
      int spins = 0;
      while (true){
        u32 f = __hip_atomic_load(&flags[lane * 4], __ATOMIC_RELAXED, __HIP_MEMORY_SCOPE_AGENT);
        if (__all((int)(f >= need))) break;
        __builtin_amdgcn_s_sleep(8);
        if (++spins > (1 << 20)) break;   // failsafe
      }
    }
    __syncthreads();

    // A-panel load: HallC rows g*128..g*128+127 (u32) -> bf16 LDS, swizzled
    {
      const u32* Am = HallC + (size_t)g * 128 * 512;
      #pragma unroll
      for (int s = 0; s < 8; ++s){
        int seg = tid + 256 * s;          // 128B segment: row = seg>>4
        int row = seg >> 4;
        u32x4 v[8];
        load_h128(Am + (size_t)seg * 32, v);
        __builtin_amdgcn_sched_barrier(0);
        #pragma unroll
        for (int j = 0; j < 8; ++j){
          int k4 = (seg & 15) * 8 + j;    // 4-elem chunk index 0..127
          uint2 pk = make_uint2((v[j][0] & 0xffffu) | (v[j][1] << 16),
                                (v[j][2] & 0xffffu) | (v[j][3] << 16));
          *(uint2*)((char*)Asm + row * 1024 + ((k4 * 8) ^ ((row & 7) << 4))) = pk;
        }
      }
    }
    __syncthreads();

    const int wm = w >> 1, wn = w & 1;
    const int sr = w * 16 + (lane >> 2);
    const int sc = (lane & 3) * 8;

    for (int n = wi; n < 250; n += 12){
      const int n0 = n * 128;
      const u16* bS = fcWbf + (size_t)(n0 + sr) * NH + sc;
      u16* bsl = Bs + w * 16 * 32;
      f32x4 acc[4][4] = {};

      gload_lds16(bS, bsl);
      gload_lds16(bS + (size_t)64 * NH, bsl + 64 * 32);
      __syncthreads();
      for (int ks = 0; ks < 16; ++ks){
        if (ks + 1 < 16){
          u16* bd = bsl + ((ks + 1) & 1) * 4096;
          gload_lds16(bS + (ks + 1) * 32, bd);
          gload_lds16(bS + (size_t)64 * NH + (ks + 1) * 32, bd + 64 * 32);
        }
        const char* Bb = (const char*)Bs + (ks & 1) * 8192;
        bf16x8 af[4], bfr[4];
        #pragma unroll
        for (int i = 0; i < 4; ++i){
          int row = wm * 64 + i * 16 + (lane & 15);
          af[i] = *(const bf16x8*)((const char*)Asm + row * 1024 +
                   ((ks * 64 + (lane >> 4) * 16) ^ ((row & 7) << 4)));
        }
        #pragma unroll
        for (int j = 0; j < 4; ++j)
          bfr[j] = *(const bf16x8*)(Bb + (wn*64 + j*16 + (lane & 15)) * 64 + (lane >> 4) * 16);
        #pragma unroll
        for (int i = 0; i < 4; ++i)
          #pragma unroll
          for (int j = 0; j < 4; ++j)
            acc[i][j] = __builtin_amdgcn_mfma_f32_16x16x32_bf16(af[i], bfr[j], acc[i][j], 0, 0, 0);
        __syncthreads();
      }

      #pragma unroll
      for (int i = 0; i < 4; ++i){
        #pragma unroll
        for (int j = 0; j < 4; ++j){
          int col = n0 + wn*64 + j*16 + (lane & 15);
          float bv = fc_b[col];
          #pragma unroll
          for (int rr = 0; rr < 4; ++rr){
            int row = g * 128 + wm*64 + i*16 + (lane >> 4) * 4 + rr;
            if (row < 2016){
              int t_ = row >> 5, b_ = row & 31;
              out[(size_t)b_ * (NT * NV) + (size_t)(t_ + 1) * NV + col] = acc[i][j][rr] + bv;
            }
          }
        }
      }
    }
  }
}

// ---------------------------------------------------------------- launcher
extern "C" void kernel_launch(void* const* d_in, const int* in_sizes, int n_in,
                              void* d_out, int out_size, void* d_ws, size_t ws_size,
                              hipStream_t stream)
{
  const int*   src      = (const int*)  d_in[0];
  const int*   trg      = (const int*)  d_in[1];
  const float* emb_enc  = (const float*)d_in[2];
  const float* W_ih_enc = (const float*)d_in[3];
  const float* W_hh_enc = (const float*)d_in[4];
  const float* b_ih_enc = (const float*)d_in[5];
  const float* b_hh_enc = (const float*)d_in[6];
  const float* emb_dec  = (const float*)d_in[7];
  const float* W_ih_dec = (const float*)d_in[8];
  const float* W_hh_dec = (const float*)d_in[9];
  const float* b_ih_dec = (const float*)d_in[10];
  const float* b_hh_dec = (const float*)d_in[11];
  const float* fc_W     = (const float*)d_in[12];
  const float* fc_b     = (const float*)d_in[13];
  float* out = (float*)d_out;

  char* ws = (char*)d_ws;
  size_t o = 0;
  auto alloc = [&](size_t bytes){ size_t r = o; o += (bytes + 255) & ~(size_t)255; return r; };
  u16*   xenc  = (u16*)(ws + alloc((size_t)2048 * NE * 2));
  u16*   xdec  = (u16*)(ws + alloc((size_t)2048 * NE * 2));   // 2016 used + 32 pad
  u16*   wihe  = (u16*)(ws + alloc((size_t)3 * NH * NE * 2));
  u16*   wihd  = (u16*)(ws + alloc((size_t)3 * NH * NE * 2));
  u16*   fcWbf = (u16*)(ws + alloc((size_t)NV * NH * 2));
  u16*   whiE  = (u16*)(ws + alloc((size_t)3 * NH * NH * 2));
  u16*   wloE  = (u16*)(ws + alloc((size_t)3 * NH * NH * 2));
  u16*   whiD  = (u16*)(ws + alloc((size_t)3 * NH * NH * 2));
  u16*   wloD  = (u16*)(ws + alloc((size_t)3 * NH * NH * 2));
  float* gie   = (float*)(ws + alloc((size_t)2048 * 3 * NH * 4));   // [t][b][1536]
  float* gid   = (float*)(ws + alloc((size_t)2048 * 3 * NH * 4));
  u32*   Hpk   = (u32*)(ws + alloc((size_t)2 * 2 * 32 * 256 * 4)); // producer blocks
  u32*   flags = (u32*)(ws + alloc(4096));
  u32*   HallC = (u32*)(ws + alloc((size_t)2048 * NH * 4));   // u32 bf16-hi, 2016 used + 32 pad

  zero_init<<<256, 256, 0, stream>>>(out, xdec + (size_t)2016 * NE, HallC + (size_t)2016 * NH, Hpk, flags);
  cvt_f32_bf16<<<384, 256, 0, stream>>>(W_ih_enc, wihe, 3*NH*NE/4);
  cvt_f32_bf16<<<384, 256, 0, stream>>>(W_ih_dec, wihd, 3*NH*NE/4);
  cvt_f32_bf16<<<2048, 256, 0, stream>>>(fc_W, fcWbf, NV*NH/4);
  cvt_hilo<<<1024, 256, 0, stream>>>(W_hh_enc, whiE, wloE, 3*NH*NH);
  cvt_hilo<<<1024, 256, 0, stream>>>(W_hh_dec, whiD, wloD, 3*NH*NH);
  embed_k<<<(NS*NB*64 + 255)/256, 256, 0, stream>>>(src, NS, NS, emb_enc, xenc);
  embed_k<<<((NT-1)*NB*64 + 255)/256, 256, 0, stream>>>(trg, NT, NT-1, emb_dec, xdec);

  // gi = x @ W_ih^T + b_ih  -> plain [t][b][1536]
  gemm_bt<NE><<<192, 256, 0, stream>>>(xenc, wihe, b_ih_enc, gie, 3*NH);
  gemm_bt<NE><<<192, 256, 0, stream>>>(xdec, wihd, b_ih_dec, gid, 3*NH);

  // fused persistent recurrence + trickle fc (256 wgs = 64 rec + 192 workers, 1/CU)
  constexpr int SMEM_REC = 2 * (GRW * NH * 2) + 2 * (BW * NH * 2) + GRW * 17 * 4;  // 134336
  constexpr int SMEM_WRK = 128 * NH * 2 + 2 * (128 * 32 * 2);                      // 147456
  constexpr int SMEM_BYTES = (SMEM_REC > SMEM_WRK) ? SMEM_REC : SMEM_WRK;
  static_assert(SMEM_BYTES <= 160 * 1024, "LDS over 160 KiB");
  static_assert(SMEM_BYTES == 147456, "unexpected LDS size");
  (void)hipFuncSetAttribute(reinterpret_cast<const void*>(&gru_fused),
                            hipFuncAttributeMaxDynamicSharedMemorySize, SMEM_BYTES);
  gru_fused<<<RG + NWK, 256, SMEM_BYTES, stream>>>(whiE, wloE, whiD, wloD, b_hh_enc, b_hh_dec,
                                                   gie, gid, Hpk, flags, HallC, fcWbf, fc_b, out);
}

// Round 17
// 701.980 us; speedup vs baseline: 1.1837x; 1.1837x over previous
//
#include <hip/hip_runtime.h>
#include <stdint.h>

constexpr int NB = 32, NS = 64, NT = 64, NV = 32000, NE = 256, NH = 512;
constexpr int RG = 64;          // recurrence wgs: 2 batch-groups x 32 unit-groups
constexpr int UW = 16;          // units per wg
constexpr int BW = 16;          // batches per wg
constexpr int GRW = 3 * UW;     // 48 gate rows per wg
constexpr int TSTEPS = NS + NT - 1;   // 127

typedef unsigned short u16;
typedef unsigned u32;
typedef short bf16x8 __attribute__((ext_vector_type(8)));
typedef float f32x4  __attribute__((ext_vector_type(4)));
typedef unsigned u32x4 __attribute__((ext_vector_type(4)));

__device__ inline u16 f2bf(float f){
  unsigned int u = __float_as_uint(f);
  u = u + 0x7FFFu + ((u >> 16) & 1u);
  return (u16)(u >> 16);
}
__device__ inline float bf2f(u16 h){ return __uint_as_float(((unsigned)h) << 16); }

__device__ inline void gload_lds16(const u16* g, u16* l){
  __builtin_amdgcn_global_load_lds((const __attribute__((address_space(1))) void*)g,
                                   (__attribute__((address_space(3))) void*)l, 16, 0, 0);
}

// W plane: 48 rows x 512 bf16. 16B chunk (r<48, k16<64):
__device__ inline int ldsW_off(int r, int k16){
  return (k16 >> 2) * 3072 + ((r >> 4) << 10) + (((((k16 & 3) << 4)) | (r & 15)) << 4);
}
// h plane: 16 rows x 512 bf16, XOR-swizzled (r10-verified 0-conflict)
__device__ inline int ldsH_off(int r, int k16){
  int base = ((k16 >> 2) << 10) + (((((k16 & 3) << 4)) | r) << 4);
  return base ^ (((base >> 10) & 15) << 4);
}

// 8 producer-block loads (2 bases, 1KB-strided imm offsets), MALL-coherent,
// waitcnt INSIDE the asm block (registers untouchable mid-asm; r5-r10-proven).
__device__ inline void load8blk(const u32* p0, const u32* p1, u32x4 v[8]){
  asm volatile(
    "global_load_dwordx4 %0, %8, off sc0 sc1\n\t"
    "global_load_dwordx4 %1, %8, off offset:1024 sc0 sc1\n\t"
    "global_load_dwordx4 %2, %8, off offset:2048 sc0 sc1\n\t"
    "global_load_dwordx4 %3, %8, off offset:3072 sc0 sc1\n\t"
    "global_load_dwordx4 %4, %9, off sc0 sc1\n\t"
    "global_load_dwordx4 %5, %9, off offset:1024 sc0 sc1\n\t"
    "global_load_dwordx4 %6, %9, off offset:2048 sc0 sc1\n\t"
    "global_load_dwordx4 %7, %9, off offset:3072 sc0 sc1\n\t"
    "s_waitcnt vmcnt(0)"
    : "=&v"(v[0]), "=&v"(v[1]), "=&v"(v[2]), "=&v"(v[3]),
      "=&v"(v[4]), "=&v"(v[5]), "=&v"(v[6]), "=&v"(v[7])
    : "v"(p0), "v"(p1)
    : "memory");
}

// ---------------------------------------------------------------- zero init
__global__ void zero_init(float* __restrict__ out, u16* __restrict__ xdecpad, u16* __restrict__ hallpad,
                          u32* __restrict__ Hpk, u32* __restrict__ flags){
  int i = blockIdx.x * blockDim.x + threadIdx.x, st = gridDim.x * blockDim.x;
  for (int idx = i; idx < NB * NV; idx += st){
    int b = idx / NV, v = idx - b * NV;
    out[(size_t)b * NT * NV + v] = 0.f;
  }
  for (int idx = i; idx < 32 * NE; idx += st) xdecpad[idx] = 0;
  for (int idx = i; idx < 32 * NH; idx += st) hallpad[idx] = 0;
  for (int idx = i; idx < 2 * 2 * 32 * 256; idx += st) Hpk[idx] = 0;  // slot0 = h(0) = 0
  for (int idx = i; idx < 1024; idx += st) flags[idx] = 0;
}

// ---------------------------------------------------------------- f32 -> bf16
__global__ void cvt_f32_bf16(const float* __restrict__ in, u16* __restrict__ out, int n4){
  int i = blockIdx.x * blockDim.x + threadIdx.x, st = gridDim.x * blockDim.x;
  for (int idx = i; idx < n4; idx += st){
    float4 v = ((const float4*)in)[idx];
    unsigned lo = (unsigned)f2bf(v.x) | ((unsigned)f2bf(v.y) << 16);
    unsigned hi = (unsigned)f2bf(v.z) | ((unsigned)f2bf(v.w) << 16);
    *(uint2*)(out + (size_t)idx * 4) = make_uint2(lo, hi);
  }
}

// ---------------------------------------------------------------- f32 -> (bf16 hi, bf16 lo)
__global__ void cvt_hilo(const float* __restrict__ in, u16* __restrict__ hi, u16* __restrict__ lo, int n){
  int i = blockIdx.x * blockDim.x + threadIdx.x, st = gridDim.x * blockDim.x;
  for (int idx = i; idx < n; idx += st){
    float w = in[idx];
    u16 h = f2bf(w);
    hi[idx] = h;
    lo[idx] = f2bf(w - bf2f(h));
  }
}

// ---------------------------------------------------------------- embedding gather (rows m = t*NB + b)
__global__ void embed_k(const int* __restrict__ idx, int ld, int tcount,
                        const float* __restrict__ emb, u16* __restrict__ xbf){
  int tid = blockIdx.x * blockDim.x + threadIdx.x;
  int n4 = tcount * NB * (NE / 4);
  if (tid >= n4) return;
  int e4 = tid & (NE/4 - 1);
  int m  = tid >> 6;
  int t = m / NB, b = m % NB;
  int row = idx[b * ld + t];
  float4 v = ((const float4*)(emb + (size_t)row * NE))[e4];
  unsigned lo = (unsigned)f2bf(v.x) | ((unsigned)f2bf(v.y) << 16);
  unsigned hi = (unsigned)f2bf(v.z) | ((unsigned)f2bf(v.w) << 16);
  *(uint2*)(xbf + (size_t)m * NE + e4 * 4) = make_uint2(lo, hi);
}

// ---------------------------------------------------------------- bf16 MFMA GEMM: C = A(MxK) * B(NxK)^T + bias
// 2-phase double-buffered. MODE 0: plain C[row*Nld+col]. MODE 1: fc scatter -> out[b][t+1][col].
template<int KDIM, int MODE>
__global__ __launch_bounds__(256) void gemm_bt(const u16* __restrict__ A,
                                               const u16* __restrict__ Bm,
                                               const float* __restrict__ bias,
                                               float* __restrict__ C,
                                               int Mstore, int Nld)
{
  __shared__ u16 As[2 * 128 * 32];
  __shared__ u16 Bs[2 * 128 * 32];
  const int id = blockIdx.x;
  const int q = gridDim.x >> 3;
  const int wg = (id & 7) * q + (id >> 3);
  const int m0 = (wg & 15) * 128, n0 = (wg >> 4) * 128;
  const int tid  = threadIdx.x;
  const int lane = tid & 63;
  const int w = tid >> 6, wm = w >> 1, wn = w & 1;
  f32x4 acc[4][4] = {};

  const int sr = w * 16 + (lane >> 2);
  const int sc = (lane & 3) * 8;
  const u16* aS = A  + (size_t)(m0 + sr) * KDIM + sc;
  const u16* bS = Bm + (size_t)(n0 + sr) * KDIM + sc;
  u16* asl = As + w * 16 * 32;
  u16* bsl = Bs + w * 16 * 32;

  auto STAGE = [&](int p, int k0){
    u16* ad = asl + p * 4096;
    u16* bd = bsl + p * 4096;
    gload_lds16(aS + k0, ad);
    gload_lds16(aS + (size_t)64 * KDIM + k0, ad + 64 * 32);
    gload_lds16(bS + k0, bd);
    gload_lds16(bS + (size_t)64 * KDIM + k0, bd + 64 * 32);
  };

  constexpr int NK = KDIM / 32;
  STAGE(0, 0);
  __syncthreads();
  for (int t2 = 0; t2 < NK; ++t2){
    if (t2 + 1 < NK) STAGE((t2 + 1) & 1, (t2 + 1) * 32);
    const char* Ab = (const char*)As + (t2 & 1) * 8192;
    const char* Bb = (const char*)Bs + (t2 & 1) * 8192;
    bf16x8 af[4], bfr[4];
    #pragma unroll
    for (int i = 0; i < 4; ++i)
      af[i] = *(const bf16x8*)(Ab + (wm*64 + i*16 + (lane & 15)) * 64 + (lane >> 4) * 16);
    #pragma unroll
    for (int j = 0; j < 4; ++j)
      bfr[j] = *(const bf16x8*)(Bb + (wn*64 + j*16 + (lane & 15)) * 64 + (lane >> 4) * 16);
    #pragma unroll
    for (int i = 0; i < 4; ++i)
      #pragma unroll
      for (int j = 0; j < 4; ++j)
        acc[i][j] = __builtin_amdgcn_mfma_f32_16x16x32_bf16(af[i], bfr[j], acc[i][j], 0, 0, 0);
    __syncthreads();
  }

  #pragma unroll
  for (int i = 0; i < 4; ++i){
    #pragma unroll
    for (int j = 0; j < 4; ++j){
      int col = n0 + wn*64 + j*16 + (lane & 15);
      float bv = bias[col];
      #pragma unroll
      for (int rr = 0; rr < 4; ++rr){
        int row = m0 + wm*64 + i*16 + (lane >> 4) * 4 + rr;
        float val = acc[i][j][rr] + bv;
        if (MODE == 1){
          if (row < Mstore){
            int t_ = row >> 5, b_ = row & 31;
            C[(size_t)b_ * (NT * NV) + (size_t)(t_ + 1) * NV + col] = val;
          }
        } else {
          C[(size_t)row * Nld + col] = val;
        }
      }
    }
  }
}

// ---------------------------------------------------------------- persistent GRU recurrence
// 64 wgs = 2 batch-groups x 32 unit-groups; wg owns 16 units x 16 batches.
// h exchange via 1KB producer blocks at MALL. Fine-grained pull: wave w waits on its
// 8 producers' flags then one-shot loads their blocks (waitcnt inside asm). The 4 waves'
// polls jointly cover all 32 cohort flags >= t before any slot overwrite (WAR-safe).
// r15 FIX: per-thread s_waitcnt vmcnt(0) after the gate-phase agent stores —
// __syncthreads (workgroup scope) does not drain relaxed AGENT stores, so without it
// the step flag can land at MALL before the h data (the r11-r14 nondeterminism).
__global__ __launch_bounds__(256) void gru_rec(
    const u16* __restrict__ WhiE, const u16* __restrict__ WloE,
    const u16* __restrict__ WhiD, const u16* __restrict__ WloD,
    const float* __restrict__ bhhE, const float* __restrict__ bhhD,
    const float* __restrict__ gie, const float* __restrict__ gid,  // [t][b][1536]
    u32* __restrict__ Hpk,            // [2][2][32][16][16] u32
    u32* __restrict__ flags,          // [64] stride 4
    u16* __restrict__ Hall)
{
  extern __shared__ char smem[];
  u16* Whi = (u16*)smem;                    // [48][512] subtiled
  u16* Wlo = Whi + GRW * NH;
  u16* Hhi = Wlo + GRW * NH;                // [16][512] subtiled+swizzled
  u16* Hlo = Hhi + BW * NH;
  float* GH = (float*)(Hlo + BW * NH);      // [48][17]

  const int tid  = threadIdx.x;
  const int lane = tid & 63;
  const int w    = tid >> 6;
  const int bg   = blockIdx.x >> 5;
  const int ug   = blockIdx.x & 31;
  const int j0   = ug * UW;
  const int b0   = bg * BW;
  const unsigned myid = blockIdx.x;

  const int gu = tid & 15, gb2 = tid >> 4;
  const int jg = j0 + gu;
  const int bglob = b0 + gb2;
  const float beR = bhhE[jg], beZ = bhhE[NH + jg], beN = bhhE[2*NH + jg];
  const float bdR = bhhD[jg], bdZ = bhhD[NH + jg], bdN = bhhD[2*NH + jg];

  auto stageW = [&](const u16* Hi, const u16* Lo){
    for (int c = tid; c < GRW * 64; c += 256){
      int r = c >> 6, k16 = c & 63;
      int grow = (r >> 4) * NH + j0 + (r & 15);
      int d = ldsW_off(r, k16);
      *(uint4*)((char*)Whi + d) = *(const uint4*)(Hi + (size_t)grow * NH + k16 * 8);
      *(uint4*)((char*)Wlo + d) = *(const uint4*)(Lo + (size_t)grow * NH + k16 * 8);
    }
  };
  stageW(WhiE, WloE);

  for (int t = 0; t < TSTEPS; ++t){
    const bool dec = (t >= NS);
    __syncthreads();                   // all threads past gate (stores drained in-loop below)
    if (tid == 0 && t > 0)
      __hip_atomic_store(&flags[myid * 4], (u32)t, __ATOMIC_RELAXED, __HIP_MEMORY_SCOPE_AGENT);
    if (t == NS) stageW(WhiD, WloD);

    // ---- pull: wave w waits for its 8 producers, then one-shot 8-block load
    {
      const u32* Hq = Hpk + (size_t)((t & 1) * 2 + bg) * 8192;
      const int fb = (bg << 5) + (w << 3);
      int spins = 0;
      while (true){
        u32 f = __hip_atomic_load(&flags[(fb + (lane & 7)) * 4], __ATOMIC_RELAXED, __HIP_MEMORY_SCOPE_AGENT);
        if (__all((int)((lane >= 8) || (w * 8 + lane == ug) || f >= (u32)t))) break;
        __builtin_amdgcn_s_sleep(1);
        if (++spins > (1 << 18)) break;   // failsafe: wrong answer, not hang
      }
      u32x4 v[8];
      const u32* p0 = Hq + ((w * 8 + 0) << 8) + lane * 4;
      const u32* p1 = Hq + ((w * 8 + 4) << 8) + lane * 4;
      load8blk(p0, p1, v);
      __builtin_amdgcn_sched_barrier(0);
      const int prow = lane >> 2, pq = lane & 3;
      #pragma unroll
      for (int p = 0; p < 8; ++p){
        u32 a0 = v[p][0], a1 = v[p][1], a2 = v[p][2], a3 = v[p][3];
        uint2 hw = make_uint2((a0 & 0xffffu) | (a1 << 16), (a2 & 0xffffu) | (a3 << 16));
        uint2 lw = make_uint2((a0 >> 16) | (a1 & 0xffff0000u), (a2 >> 16) | (a3 & 0xffff0000u));
        int k16 = (w * 8 + p) * 2 + (pq >> 1);
        int d = ldsH_off(prow, k16) + (pq & 1) * 8;
        *(uint2*)((char*)Hhi + d) = hw;
        *(uint2*)((char*)Hlo + d) = lw;
      }
    }
    __syncthreads();

    const float* gp = (dec ? (gid + ((size_t)(t - NS) * NB + bglob) * 1536)
                           : (gie + ((size_t)t * NB + bglob) * 1536));
    float gr = gp[jg], gz = gp[NH + jg], gn = gp[2 * NH + jg];

    if (w < 3){
      f32x4 acc0 = {0.f,0.f,0.f,0.f}, acc1 = {0.f,0.f,0.f,0.f};
      const int ab = w * 1024 + lane * 16;
      const int bb = lane * 16;
      #pragma unroll
      for (int kk = 0; kk < 16; kk += 2){
        const int bx0 = kk * 1024 + (bb ^ ((kk & 15) << 4));
        const int bx1 = (kk+1) * 1024 + (bb ^ (((kk+1) & 15) << 4));
        bf16x8 ah0 = *(const bf16x8*)((const char*)Whi + kk * 3072 + ab);
        bf16x8 al0 = *(const bf16x8*)((const char*)Wlo + kk * 3072 + ab);
        bf16x8 bh0 = *(const bf16x8*)((const char*)Hhi + bx0);
        bf16x8 bl0 = *(const bf16x8*)((const char*)Hlo + bx0);
        acc0 = __builtin_amdgcn_mfma_f32_16x16x32_bf16(ah0, bh0, acc0, 0, 0, 0);
        acc0 = __builtin_amdgcn_mfma_f32_16x16x32_bf16(al0, bh0, acc0, 0, 0, 0);
        acc0 = __builtin_amdgcn_mfma_f32_16x16x32_bf16(ah0, bl0, acc0, 0, 0, 0);
        bf16x8 ah1 = *(const bf16x8*)((const char*)Whi + (kk+1) * 3072 + ab);
        bf16x8 al1 = *(const bf16x8*)((const char*)Wlo + (kk+1) * 3072 + ab);
        bf16x8 bh1 = *(const bf16x8*)((const char*)Hhi + bx1);
        bf16x8 bl1 = *(const bf16x8*)((const char*)Hlo + bx1);
        acc1 = __builtin_amdgcn_mfma_f32_16x16x32_bf16(ah1, bh1, acc1, 0, 0, 0);
        acc1 = __builtin_amdgcn_mfma_f32_16x16x32_bf16(al1, bh1, acc1, 0, 0, 0);
        acc1 = __builtin_amdgcn_mfma_f32_16x16x32_bf16(ah1, bl1, acc1, 0, 0, 0);
      }
      f32x4 accs = acc0 + acc1;
      int col = lane & 15;
      #pragma unroll
      for (int r2 = 0; r2 < 4; ++r2){
        int row = w * 16 + ((lane >> 4) << 2) + r2;
        GH[row * 17 + col] = accs[r2];
      }
    }
    __syncthreads();

    {
      float ghr = GH[(0 * UW + gu) * 17 + gb2] + (dec ? bdR : beR);
      float ghz = GH[(1 * UW + gu) * 17 + gb2] + (dec ? bdZ : beZ);
      float ghn = GH[(2 * UW + gu) * 17 + gb2] + (dec ? bdN : beN);
      float r = 1.f / (1.f + expf(-(gr + ghr)));
      float z = 1.f / (1.f + expf(-(gz + ghz)));
      float n = tanhf(gn + r * ghn);
      int coff = ldsH_off(gb2, jg >> 3) + (jg & 7) * 2;
      float hp = bf2f(*(const u16*)((char*)Hhi + coff))
               + bf2f(*(const u16*)((char*)Hlo + coff));
      float hnew = (1.f - z) * n + z * hp;
      u16 hi = f2bf(hnew);
      u16 lo = f2bf(hnew - bf2f(hi));
      if (dec) Hall[((size_t)(t - NS) * NB + bglob) * NH + jg] = hi;
      if (t < TSTEPS - 1){
        u32* dst = Hpk + (size_t)((((t + 1) & 1) * 2 + bg) * 32 + ug) * 256 + gb2 * 16 + gu;
        __hip_atomic_store(dst, (u32)hi | ((u32)lo << 16),
                           __ATOMIC_RELAXED, __HIP_MEMORY_SCOPE_AGENT);
      }
      // r15 FIX: drain h/Hall stores to the coherence point in EVERY thread before
      // the barrier that precedes the flag publish.
      asm volatile("s_waitcnt vmcnt(0)" ::: "memory");
    }
  }
}

// ---------------------------------------------------------------- launcher
extern "C" void kernel_launch(void* const* d_in, const int* in_sizes, int n_in,
                              void* d_out, int out_size, void* d_ws, size_t ws_size,
                              hipStream_t stream)
{
  const int*   src      = (const int*)  d_in[0];
  const int*   trg      = (const int*)  d_in[1];
  const float* emb_enc  = (const float*)d_in[2];
  const float* W_ih_enc = (const float*)d_in[3];
  const float* W_hh_enc = (const float*)d_in[4];
  const float* b_ih_enc = (const float*)d_in[5];
  const float* b_hh_enc = (const float*)d_in[6];
  const float* emb_dec  = (const float*)d_in[7];
  const float* W_ih_dec = (const float*)d_in[8];
  const float* W_hh_dec = (const float*)d_in[9];
  const float* b_ih_dec = (const float*)d_in[10];
  const float* b_hh_dec = (const float*)d_in[11];
  const float* fc_W     = (const float*)d_in[12];
  const float* fc_b     = (const float*)d_in[13];
  float* out = (float*)d_out;

  char* ws = (char*)d_ws;
  size_t o = 0;
  auto alloc = [&](size_t bytes){ size_t r = o; o += (bytes + 255) & ~(size_t)255; return r; };
  u16*   xenc  = (u16*)(ws + alloc((size_t)2048 * NE * 2));
  u16*   xdec  = (u16*)(ws + alloc((size_t)2048 * NE * 2));   // 2016 used + 32 pad
  u16*   wihe  = (u16*)(ws + alloc((size_t)3 * NH * NE * 2));
  u16*   wihd  = (u16*)(ws + alloc((size_t)3 * NH * NE * 2));
  u16*   fcWbf = (u16*)(ws + alloc((size_t)NV * NH * 2));
  u16*   whiE  = (u16*)(ws + alloc((size_t)3 * NH * NH * 2));
  u16*   wloE  = (u16*)(ws + alloc((size_t)3 * NH * NH * 2));
  u16*   whiD  = (u16*)(ws + alloc((size_t)3 * NH * NH * 2));
  u16*   wloD  = (u16*)(ws + alloc((size_t)3 * NH * NH * 2));
  float* gie   = (float*)(ws + alloc((size_t)2048 * 3 * NH * 4));   // [t][b][1536]
  float* gid   = (float*)(ws + alloc((size_t)2048 * 3 * NH * 4));
  u32*   Hpk   = (u32*)(ws + alloc((size_t)2 * 2 * 32 * 256 * 4)); // producer blocks
  u32*   flags = (u32*)(ws + alloc(4096));
  u16*   Hall  = (u16*)(ws + alloc((size_t)2048 * NH * 2));   // 2016 used + 32 pad

  zero_init<<<256, 256, 0, stream>>>(out, xdec + (size_t)2016 * NE, Hall + (size_t)2016 * NH, Hpk, flags);
  cvt_f32_bf16<<<384, 256, 0, stream>>>(W_ih_enc, wihe, 3*NH*NE/4);
  cvt_f32_bf16<<<384, 256, 0, stream>>>(W_ih_dec, wihd, 3*NH*NE/4);
  cvt_f32_bf16<<<2048, 256, 0, stream>>>(fc_W, fcWbf, NV*NH/4);
  cvt_hilo<<<1024, 256, 0, stream>>>(W_hh_enc, whiE, wloE, 3*NH*NH);
  cvt_hilo<<<1024, 256, 0, stream>>>(W_hh_dec, whiD, wloD, 3*NH*NH);
  embed_k<<<(NS*NB*64 + 255)/256, 256, 0, stream>>>(src, NS, NS, emb_enc, xenc);
  embed_k<<<((NT-1)*NB*64 + 255)/256, 256, 0, stream>>>(trg, NT, NT-1, emb_dec, xdec);

  // gi = x @ W_ih^T + b_ih  -> plain [t][b][1536]
  gemm_bt<NE, 0><<<192, 256, 0, stream>>>(xenc, wihe, b_ih_enc, gie, 2048, 3*NH);
  gemm_bt<NE, 0><<<192, 256, 0, stream>>>(xdec, wihd, b_ih_dec, gid, 2048, 3*NH);

  // persistent recurrence
  // LDS: W hi+lo 2*49152 + h hi+lo 2*16384 + GH 48*17*4 = 134336
  constexpr int SMEM_BYTES = 2 * (GRW * NH * 2) + 2 * (BW * NH * 2) + GRW * 17 * 4;
  static_assert(SMEM_BYTES <= 160 * 1024, "LDS over 160 KiB");
  static_assert(SMEM_BYTES == 134336, "unexpected LDS size");
  (void)hipFuncSetAttribute(reinterpret_cast<const void*>(&gru_rec),
                            hipFuncAttributeMaxDynamicSharedMemorySize, SMEM_BYTES);
  gru_rec<<<RG, 256, SMEM_BYTES, stream>>>(whiE, wloE, whiD, wloD, b_hh_enc, b_hh_dec,
                                           gie, gid, Hpk, flags, Hall);

  // logits = h2 @ fc_W^T + fc_b  (M=2048 pad, N=32000, K=512)
  gemm_bt<NH, 1><<<4000, 256, 0, stream>>>(Hall, fcWbf, fc_b, out, 2016, 0);
}

// Round 18
// 668.354 us; speedup vs baseline: 1.2432x; 1.0503x over previous
//
#include <hip/hip_runtime.h>
#include <stdint.h>

constexpr int NB = 32, NS = 64, NT = 64, NV = 32000, NE = 256, NH = 512;
constexpr int RG = 64;          // recurrence wgs: 2 batch-groups x 32 unit-groups
constexpr int UW = 16;          // units per wg
constexpr int BW = 16;          // batches per wg
constexpr int GRW = 3 * UW;     // 48 gate rows per wg
constexpr int TSTEPS = NS + NT - 1;   // 127

typedef unsigned short u16;
typedef unsigned u32;
typedef short bf16x8 __attribute__((ext_vector_type(8)));
typedef float f32x4  __attribute__((ext_vector_type(4)));
typedef unsigned u32x4 __attribute__((ext_vector_type(4)));

__device__ inline u16 f2bf(float f){
  unsigned int u = __float_as_uint(f);
  u = u + 0x7FFFu + ((u >> 16) & 1u);
  return (u16)(u >> 16);
}
__device__ inline float bf2f(u16 h){ return __uint_as_float(((unsigned)h) << 16); }

__device__ inline void gload_lds16(const u16* g, u16* l){
  __builtin_amdgcn_global_load_lds((const __attribute__((address_space(1))) void*)g,
                                   (__attribute__((address_space(3))) void*)l, 16, 0, 0);
}

// W plane: 48 rows x 512 bf16. 16B chunk (r<48, k16<64):
__device__ inline int ldsW_off(int r, int k16){
  return (k16 >> 2) * 3072 + ((r >> 4) << 10) + (((((k16 & 3) << 4)) | (r & 15)) << 4);
}
// h plane: 16 rows x 512 bf16, XOR-swizzled (r10-verified 0-conflict)
__device__ inline int ldsH_off(int r, int k16){
  int base = ((k16 >> 2) << 10) + (((((k16 & 3) << 4)) | r) << 4);
  return base ^ (((base >> 10) & 15) << 4);
}

// 8 producer-block loads (2 bases, 1KB-strided imm offsets), MALL-coherent,
// waitcnt INSIDE the asm block (registers untouchable mid-asm; r5-r10-proven).
__device__ inline void load8blk(const u32* p0, const u32* p1, u32x4 v[8]){
  asm volatile(
    "global_load_dwordx4 %0, %8, off sc0 sc1\n\t"
    "global_load_dwordx4 %1, %8, off offset:1024 sc0 sc1\n\t"
    "global_load_dwordx4 %2, %8, off offset:2048 sc0 sc1\n\t"
    "global_load_dwordx4 %3, %8, off offset:3072 sc0 sc1\n\t"
    "global_load_dwordx4 %4, %9, off sc0 sc1\n\t"
    "global_load_dwordx4 %5, %9, off offset:1024 sc0 sc1\n\t"
    "global_load_dwordx4 %6, %9, off offset:2048 sc0 sc1\n\t"
    "global_load_dwordx4 %7, %9, off offset:3072 sc0 sc1\n\t"
    "s_waitcnt vmcnt(0)"
    : "=&v"(v[0]), "=&v"(v[1]), "=&v"(v[2]), "=&v"(v[3]),
      "=&v"(v[4]), "=&v"(v[5]), "=&v"(v[6]), "=&v"(v[7])
    : "v"(p0), "v"(p1)
    : "memory");
}

// ---------------------------------------------------------------- zero init
__global__ void zero_init(float* __restrict__ out, u16* __restrict__ xdecpad, u16* __restrict__ hallpad,
                          u32* __restrict__ Hpk, u32* __restrict__ flags){
  int i = blockIdx.x * blockDim.x + threadIdx.x, st = gridDim.x * blockDim.x;
  for (int idx = i; idx < NB * NV; idx += st){
    int b = idx / NV, v = idx - b * NV;
    out[(size_t)b * NT * NV + v] = 0.f;
  }
  for (int idx = i; idx < 32 * NE; idx += st) xdecpad[idx] = 0;
  for (int idx = i; idx < 32 * NH; idx += st) hallpad[idx] = 0;
  for (int idx = i; idx < 2 * 2 * 32 * 256; idx += st) Hpk[idx] = 0;  // slot0 = h(0) = 0
  for (int idx = i; idx < 1024; idx += st) flags[idx] = 0;
}

// ---------------------------------------------------------------- f32 -> bf16
__global__ void cvt_f32_bf16(const float* __restrict__ in, u16* __restrict__ out, int n4){
  int i = blockIdx.x * blockDim.x + threadIdx.x, st = gridDim.x * blockDim.x;
  for (int idx = i; idx < n4; idx += st){
    float4 v = ((const float4*)in)[idx];
    unsigned lo = (unsigned)f2bf(v.x) | ((unsigned)f2bf(v.y) << 16);
    unsigned hi = (unsigned)f2bf(v.z) | ((unsigned)f2bf(v.w) << 16);
    *(uint2*)(out + (size_t)idx * 4) = make_uint2(lo, hi);
  }
}

// ---------------------------------------------------------------- f32 -> (bf16 hi, bf16 lo)
__global__ void cvt_hilo(const float* __restrict__ in, u16* __restrict__ hi, u16* __restrict__ lo, int n){
  int i = blockIdx.x * blockDim.x + threadIdx.x, st = gridDim.x * blockDim.x;
  for (int idx = i; idx < n; idx += st){
    float w = in[idx];
    u16 h = f2bf(w);
    hi[idx] = h;
    lo[idx] = f2bf(w - bf2f(h));
  }
}

// ---------------------------------------------------------------- embedding gather (rows m = t*NB + b)
__global__ void embed_k(const int* __restrict__ idx, int ld, int tcount,
                        const float* __restrict__ emb, u16* __restrict__ xbf){
  int tid = blockIdx.x * blockDim.x + threadIdx.x;
  int n4 = tcount * NB * (NE / 4);
  if (tid >= n4) return;
  int e4 = tid & (NE/4 - 1);
  int m  = tid >> 6;
  int t = m / NB, b = m % NB;
  int row = idx[b * ld + t];
  float4 v = ((const float4*)(emb + (size_t)row * NE))[e4];
  unsigned lo = (unsigned)f2bf(v.x) | ((unsigned)f2bf(v.y) << 16);
  unsigned hi = (unsigned)f2bf(v.z) | ((unsigned)f2bf(v.w) << 16);
  *(uint2*)(xbf + (size_t)m * NE + e4 * 4) = make_uint2(lo, hi);
}

// ---------------------------------------------------------------- bf16 MFMA GEMM (gi): 128x128 tile, plain store
template<int KDIM>
__global__ __launch_bounds__(256) void gemm_bt(const u16* __restrict__ A,
                                               const u16* __restrict__ Bm,
                                               const float* __restrict__ bias,
                                               float* __restrict__ C, int Nld)
{
  __shared__ u16 As[2 * 128 * 32];
  __shared__ u16 Bs[2 * 128 * 32];
  const int id = blockIdx.x;
  const int q = gridDim.x >> 3;
  const int wg = (id & 7) * q + (id >> 3);
  const int m0 = (wg & 15) * 128, n0 = (wg >> 4) * 128;
  const int tid  = threadIdx.x;
  const int lane = tid & 63;
  const int w = tid >> 6, wm = w >> 1, wn = w & 1;
  f32x4 acc[4][4] = {};

  const int sr = w * 16 + (lane >> 2);
  const int sc = (lane & 3) * 8;
  const u16* aS = A  + (size_t)(m0 + sr) * KDIM + sc;
  const u16* bS = Bm + (size_t)(n0 + sr) * KDIM + sc;
  u16* asl = As + w * 16 * 32;
  u16* bsl = Bs + w * 16 * 32;

  auto STAGE = [&](int p, int k0){
    u16* ad = asl + p * 4096;
    u16* bd = bsl + p * 4096;
    gload_lds16(aS + k0, ad);
    gload_lds16(aS + (size_t)64 * KDIM + k0, ad + 64 * 32);
    gload_lds16(bS + k0, bd);
    gload_lds16(bS + (size_t)64 * KDIM + k0, bd + 64 * 32);
  };

  constexpr int NK = KDIM / 32;
  STAGE(0, 0);
  __syncthreads();
  for (int t2 = 0; t2 < NK; ++t2){
    if (t2 + 1 < NK) STAGE((t2 + 1) & 1, (t2 + 1) * 32);
    const char* Ab = (const char*)As + (t2 & 1) * 8192;
    const char* Bb = (const char*)Bs + (t2 & 1) * 8192;
    bf16x8 af[4], bfr[4];
    #pragma unroll
    for (int i = 0; i < 4; ++i)
      af[i] = *(const bf16x8*)(Ab + (wm*64 + i*16 + (lane & 15)) * 64 + (lane >> 4) * 16);
    #pragma unroll
    for (int j = 0; j < 4; ++j)
      bfr[j] = *(const bf16x8*)(Bb + (wn*64 + j*16 + (lane & 15)) * 64 + (lane >> 4) * 16);
    #pragma unroll
    for (int i = 0; i < 4; ++i)
      #pragma unroll
      for (int j = 0; j < 4; ++j)
        acc[i][j] = __builtin_amdgcn_mfma_f32_16x16x32_bf16(af[i], bfr[j], acc[i][j], 0, 0, 0);
    __syncthreads();
  }

  #pragma unroll
  for (int i = 0; i < 4; ++i){
    #pragma unroll
    for (int j = 0; j < 4; ++j){
      int col = n0 + wn*64 + j*16 + (lane & 15);
      float bv = bias[col];
      #pragma unroll
      for (int rr = 0; rr < 4; ++rr){
        int row = m0 + wm*64 + i*16 + (lane >> 4) * 4 + rr;
        C[(size_t)row * Nld + col] = acc[i][j][rr] + bv;
      }
    }
  }
}

// ---------------------------------------------------------------- fc GEMM: 256x256 tile, 512 thr / 8 waves
// K = NH = 512, 2-phase double-buffered global_load_lds staging. Wave (wm,wn) = 128x64
// output subtile, acc[8][4]. Same MFMA shape + k-order as the 128^2 kernel -> output
// bit-identical. Scatter row m = t*NB+b -> out[b][t+1][col].
__global__ __launch_bounds__(512) void gemm_fc256(const u16* __restrict__ A,
                                                  const u16* __restrict__ Bm,
                                                  const float* __restrict__ bias,
                                                  float* __restrict__ C, int Mstore)
{
  extern __shared__ char smem[];
  u16* As = (u16*)smem;                 // 2 x [256][32] bf16 = 32 KB
  u16* Bs = As + 2 * 256 * 32;          // 2 x [256][32] bf16 = 32 KB
  const int id = blockIdx.x;
  const int q = gridDim.x >> 3;         // 125 (grid 1000, %8 == 0 -> bijective swizzle)
  const int wg = (id & 7) * q + (id >> 3);
  const int m0 = (wg & 7) * 256, n0 = (wg >> 3) * 256;
  const int tid  = threadIdx.x;
  const int lane = tid & 63;
  const int w = tid >> 6;               // 0..7
  const int wm = w >> 2, wn = w & 3;
  f32x4 acc[8][4] = {};

  const int sr = w * 16 + (lane >> 2);  // staging row 0..127
  const int sc = (lane & 3) * 8;
  const u16* aS = A  + (size_t)(m0 + sr) * NH + sc;
  const u16* bS = Bm + (size_t)(n0 + sr) * NH + sc;
  u16* asl = As + w * 16 * 32;
  u16* bsl = Bs + w * 16 * 32;

  auto STAGE = [&](int p, int k0){
    u16* ad = asl + p * 8192;
    u16* bd = bsl + p * 8192;
    gload_lds16(aS + k0, ad);
    gload_lds16(aS + (size_t)128 * NH + k0, ad + 128 * 32);
    gload_lds16(bS + k0, bd);
    gload_lds16(bS + (size_t)128 * NH + k0, bd + 128 * 32);
  };

  STAGE(0, 0);
  __syncthreads();
  for (int t2 = 0; t2 < 16; ++t2){
    if (t2 + 1 < 16) STAGE((t2 + 1) & 1, (t2 + 1) * 32);
    const char* Ab = (const char*)As + (t2 & 1) * 16384;
    const char* Bb = (const char*)Bs + (t2 & 1) * 16384;
    bf16x8 af[8], bfr[4];
    #pragma unroll
    for (int i = 0; i < 8; ++i)
      af[i] = *(const bf16x8*)(Ab + (wm*128 + i*16 + (lane & 15)) * 64 + (lane >> 4) * 16);
    #pragma unroll
    for (int j = 0; j < 4; ++j)
      bfr[j] = *(const bf16x8*)(Bb + (wn*64 + j*16 + (lane & 15)) * 64 + (lane >> 4) * 16);
    #pragma unroll
    for (int i = 0; i < 8; ++i)
      #pragma unroll
      for (int j = 0; j < 4; ++j)
        acc[i][j] = __builtin_amdgcn_mfma_f32_16x16x32_bf16(af[i], bfr[j], acc[i][j], 0, 0, 0);
    __syncthreads();
  }

  #pragma unroll
  for (int i = 0; i < 8; ++i){
    #pragma unroll
    for (int j = 0; j < 4; ++j){
      int col = n0 + wn*64 + j*16 + (lane & 15);
      float bv = bias[col];
      #pragma unroll
      for (int rr = 0; rr < 4; ++rr){
        int row = m0 + wm*128 + i*16 + (lane >> 4) * 4 + rr;
        if (row < Mstore){
          int t_ = row >> 5, b_ = row & 31;
          C[(size_t)b_ * (NT * NV) + (size_t)(t_ + 1) * NV + col] = acc[i][j][rr] + bv;
        }
      }
    }
  }
}

// ---------------------------------------------------------------- persistent GRU recurrence (r17, verified)
__global__ __launch_bounds__(256) void gru_rec(
    const u16* __restrict__ WhiE, const u16* __restrict__ WloE,
    const u16* __restrict__ WhiD, const u16* __restrict__ WloD,
    const float* __restrict__ bhhE, const float* __restrict__ bhhD,
    const float* __restrict__ gie, const float* __restrict__ gid,  // [t][b][1536]
    u32* __restrict__ Hpk,            // [2][2][32][16][16] u32
    u32* __restrict__ flags,          // [64] stride 4
    u16* __restrict__ Hall)
{
  extern __shared__ char smem[];
  u16* Whi = (u16*)smem;                    // [48][512] subtiled
  u16* Wlo = Whi + GRW * NH;
  u16* Hhi = Wlo + GRW * NH;                // [16][512] subtiled+swizzled
  u16* Hlo = Hhi + BW * NH;
  float* GH = (float*)(Hlo + BW * NH);      // [48][17]

  const int tid  = threadIdx.x;
  const int lane = tid & 63;
  const int w    = tid >> 6;
  const int bg   = blockIdx.x >> 5;
  const int ug   = blockIdx.x & 31;
  const int j0   = ug * UW;
  const int b0   = bg * BW;
  const unsigned myid = blockIdx.x;

  const int gu = tid & 15, gb2 = tid >> 4;
  const int jg = j0 + gu;
  const int bglob = b0 + gb2;
  const float beR = bhhE[jg], beZ = bhhE[NH + jg], beN = bhhE[2*NH + jg];
  const float bdR = bhhD[jg], bdZ = bhhD[NH + jg], bdN = bhhD[2*NH + jg];

  auto stageW = [&](const u16* Hi, const u16* Lo){
    for (int c = tid; c < GRW * 64; c += 256){
      int r = c >> 6, k16 = c & 63;
      int grow = (r >> 4) * NH + j0 + (r & 15);
      int d = ldsW_off(r, k16);
      *(uint4*)((char*)Whi + d) = *(const uint4*)(Hi + (size_t)grow * NH + k16 * 8);
      *(uint4*)((char*)Wlo + d) = *(const uint4*)(Lo + (size_t)grow * NH + k16 * 8);
    }
  };
  stageW(WhiE, WloE);

  for (int t = 0; t < TSTEPS; ++t){
    const bool dec = (t >= NS);
    __syncthreads();                   // all threads past gate (stores drained in-loop below)
    if (tid == 0 && t > 0)
      __hip_atomic_store(&flags[myid * 4], (u32)t, __ATOMIC_RELAXED, __HIP_MEMORY_SCOPE_AGENT);
    if (t == NS) stageW(WhiD, WloD);

    // ---- pull: wave w waits for its 8 producers, then one-shot 8-block load
    {
      const u32* Hq = Hpk + (size_t)((t & 1) * 2 + bg) * 8192;
      const int fb = (bg << 5) + (w << 3);
      int spins = 0;
      while (true){
        u32 f = __hip_atomic_load(&flags[(fb + (lane & 7)) * 4], __ATOMIC_RELAXED, __HIP_MEMORY_SCOPE_AGENT);
        if (__all((int)((lane >= 8) || (w * 8 + lane == ug) || f >= (u32)t))) break;
        __builtin_amdgcn_s_sleep(1);
        if (++spins > (1 << 18)) break;   // failsafe: wrong answer, not hang
      }
      u32x4 v[8];
      const u32* p0 = Hq + ((w * 8 + 0) << 8) + lane * 4;
      const u32* p1 = Hq + ((w * 8 + 4) << 8) + lane * 4;
      load8blk(p0, p1, v);
      __builtin_amdgcn_sched_barrier(0);
      const int prow = lane >> 2, pq = lane & 3;
      #pragma unroll
      for (int p = 0; p < 8; ++p){
        u32 a0 = v[p][0], a1 = v[p][1], a2 = v[p][2], a3 = v[p][3];
        uint2 hw = make_uint2((a0 & 0xffffu) | (a1 << 16), (a2 & 0xffffu) | (a3 << 16));
        uint2 lw = make_uint2((a0 >> 16) | (a1 & 0xffff0000u), (a2 >> 16) | (a3 & 0xffff0000u));
        int k16 = (w * 8 + p) * 2 + (pq >> 1);
        int d = ldsH_off(prow, k16) + (pq & 1) * 8;
        *(uint2*)((char*)Hhi + d) = hw;
        *(uint2*)((char*)Hlo + d) = lw;
      }
    }
    __syncthreads();

    const float* gp = (dec ? (gid + ((size_t)(t - NS) * NB + bglob) * 1536)
                           : (gie + ((size_t)t * NB + bglob) * 1536));
    float gr = gp[jg], gz = gp[NH + jg], gn = gp[2 * NH + jg];

    if (w < 3){
      f32x4 acc0 = {0.f,0.f,0.f,0.f}, acc1 = {0.f,0.f,0.f,0.f};
      const int ab = w * 1024 + lane * 16;
      const int bb = lane * 16;
      #pragma unroll
      for (int kk = 0; kk < 16; kk += 2){
        const int bx0 = kk * 1024 + (bb ^ ((kk & 15) << 4));
        const int bx1 = (kk+1) * 1024 + (bb ^ (((kk+1) & 15) << 4));
        bf16x8 ah0 = *(const bf16x8*)((const char*)Whi + kk * 3072 + ab);
        bf16x8 al0 = *(const bf16x8*)((const char*)Wlo + kk * 3072 + ab);
        bf16x8 bh0 = *(const bf16x8*)((const char*)Hhi + bx0);
        bf16x8 bl0 = *(const bf16x8*)((const char*)Hlo + bx0);
        acc0 = __builtin_amdgcn_mfma_f32_16x16x32_bf16(ah0, bh0, acc0, 0, 0, 0);
        acc0 = __builtin_amdgcn_mfma_f32_16x16x32_bf16(al0, bh0, acc0, 0, 0, 0);
        acc0 = __builtin_amdgcn_mfma_f32_16x16x32_bf16(ah0, bl0, acc0, 0, 0, 0);
        bf16x8 ah1 = *(const bf16x8*)((const char*)Whi + (kk+1) * 3072 + ab);
        bf16x8 al1 = *(const bf16x8*)((const char*)Wlo + (kk+1) * 3072 + ab);
        bf16x8 bh1 = *(const bf16x8*)((const char*)Hhi + bx1);
        bf16x8 bl1 = *(const bf16x8*)((const char*)Hlo + bx1);
        acc1 = __builtin_amdgcn_mfma_f32_16x16x32_bf16(ah1, bh1, acc1, 0, 0, 0);
        acc1 = __builtin_amdgcn_mfma_f32_16x16x32_bf16(al1, bh1, acc1, 0, 0, 0);
        acc1 = __builtin_amdgcn_mfma_f32_16x16x32_bf16(ah1, bl1, acc1, 0, 0, 0);
      }
      f32x4 accs = acc0 + acc1;
      int col = lane & 15;
      #pragma unroll
      for (int r2 = 0; r2 < 4; ++r2){
        int row = w * 16 + ((lane >> 4) << 2) + r2;
        GH[row * 17 + col] = accs[r2];
      }
    }
    __syncthreads();

    {
      float ghr = GH[(0 * UW + gu) * 17 + gb2] + (dec ? bdR : beR);
      float ghz = GH[(1 * UW + gu) * 17 + gb2] + (dec ? bdZ : beZ);
      float ghn = GH[(2 * UW + gu) * 17 + gb2] + (dec ? bdN : beN);
      float r = 1.f / (1.f + expf(-(gr + ghr)));
      float z = 1.f / (1.f + expf(-(gz + ghz)));
      float n = tanhf(gn + r * ghn);
      int coff = ldsH_off(gb2, jg >> 3) + (jg & 7) * 2;
      float hp = bf2f(*(const u16*)((char*)Hhi + coff))
               + bf2f(*(const u16*)((char*)Hlo + coff));
      float hnew = (1.f - z) * n + z * hp;
      u16 hi = f2bf(hnew);
      u16 lo = f2bf(hnew - bf2f(hi));
      if (dec) Hall[((size_t)(t - NS) * NB + bglob) * NH + jg] = hi;
      if (t < TSTEPS - 1){
        u32* dst = Hpk + (size_t)((((t + 1) & 1) * 2 + bg) * 32 + ug) * 256 + gb2 * 16 + gu;
        __hip_atomic_store(dst, (u32)hi | ((u32)lo << 16),
                           __ATOMIC_RELAXED, __HIP_MEMORY_SCOPE_AGENT);
      }
      // r15 FIX: drain h/Hall stores to the coherence point in EVERY thread before
      // the barrier that precedes the flag publish.
      asm volatile("s_waitcnt vmcnt(0)" ::: "memory");
    }
  }
}

// ---------------------------------------------------------------- launcher
extern "C" void kernel_launch(void* const* d_in, const int* in_sizes, int n_in,
                              void* d_out, int out_size, void* d_ws, size_t ws_size,
                              hipStream_t stream)
{
  const int*   src      = (const int*)  d_in[0];
  const int*   trg      = (const int*)  d_in[1];
  const float* emb_enc  = (const float*)d_in[2];
  const float* W_ih_enc = (const float*)d_in[3];
  const float* W_hh_enc = (const float*)d_in[4];
  const float* b_ih_enc = (const float*)d_in[5];
  const float* b_hh_enc = (const float*)d_in[6];
  const float* emb_dec  = (const float*)d_in[7];
  const float* W_ih_dec = (const float*)d_in[8];
  const float* W_hh_dec = (const float*)d_in[9];
  const float* b_ih_dec = (const float*)d_in[10];
  const float* b_hh_dec = (const float*)d_in[11];
  const float* fc_W     = (const float*)d_in[12];
  const float* fc_b     = (const float*)d_in[13];
  float* out = (float*)d_out;

  char* ws = (char*)d_ws;
  size_t o = 0;
  auto alloc = [&](size_t bytes){ size_t r = o; o += (bytes + 255) & ~(size_t)255; return r; };
  u16*   xenc  = (u16*)(ws + alloc((size_t)2048 * NE * 2));
  u16*   xdec  = (u16*)(ws + alloc((size_t)2048 * NE * 2));   // 2016 used + 32 pad
  u16*   wihe  = (u16*)(ws + alloc((size_t)3 * NH * NE * 2));
  u16*   wihd  = (u16*)(ws + alloc((size_t)3 * NH * NE * 2));
  u16*   fcWbf = (u16*)(ws + alloc((size_t)NV * NH * 2));
  u16*   whiE  = (u16*)(ws + alloc((size_t)3 * NH * NH * 2));
  u16*   wloE  = (u16*)(ws + alloc((size_t)3 * NH * NH * 2));
  u16*   whiD  = (u16*)(ws + alloc((size_t)3 * NH * NH * 2));
  u16*   wloD  = (u16*)(ws + alloc((size_t)3 * NH * NH * 2));
  float* gie   = (float*)(ws + alloc((size_t)2048 * 3 * NH * 4));   // [t][b][1536]
  float* gid   = (float*)(ws + alloc((size_t)2048 * 3 * NH * 4));
  u32*   Hpk   = (u32*)(ws + alloc((size_t)2 * 2 * 32 * 256 * 4)); // producer blocks
  u32*   flags = (u32*)(ws + alloc(4096));
  u16*   Hall  = (u16*)(ws + alloc((size_t)2048 * NH * 2));   // 2016 used + 32 pad

  zero_init<<<256, 256, 0, stream>>>(out, xdec + (size_t)2016 * NE, Hall + (size_t)2016 * NH, Hpk, flags);
  cvt_f32_bf16<<<384, 256, 0, stream>>>(W_ih_enc, wihe, 3*NH*NE/4);
  cvt_f32_bf16<<<384, 256, 0, stream>>>(W_ih_dec, wihd, 3*NH*NE/4);
  cvt_f32_bf16<<<2048, 256, 0, stream>>>(fc_W, fcWbf, NV*NH/4);
  cvt_hilo<<<1024, 256, 0, stream>>>(W_hh_enc, whiE, wloE, 3*NH*NH);
  cvt_hilo<<<1024, 256, 0, stream>>>(W_hh_dec, whiD, wloD, 3*NH*NH);
  embed_k<<<(NS*NB*64 + 255)/256, 256, 0, stream>>>(src, NS, NS, emb_enc, xenc);
  embed_k<<<((NT-1)*NB*64 + 255)/256, 256, 0, stream>>>(trg, NT, NT-1, emb_dec, xdec);

  // gi = x @ W_ih^T + b_ih  -> plain [t][b][1536]
  gemm_bt<NE><<<192, 256, 0, stream>>>(xenc, wihe, b_ih_enc, gie, 3*NH);
  gemm_bt<NE><<<192, 256, 0, stream>>>(xdec, wihd, b_ih_dec, gid, 3*NH);

  // persistent recurrence (r17-verified deterministic)
  constexpr int SMEM_BYTES = 2 * (GRW * NH * 2) + 2 * (BW * NH * 2) + GRW * 17 * 4;
  static_assert(SMEM_BYTES <= 160 * 1024, "LDS over 160 KiB");
  static_assert(SMEM_BYTES == 134336, "unexpected LDS size");
  (void)hipFuncSetAttribute(reinterpret_cast<const void*>(&gru_rec),
                            hipFuncAttributeMaxDynamicSharedMemorySize, SMEM_BYTES);
  gru_rec<<<RG, 256, SMEM_BYTES, stream>>>(whiE, wloE, whiD, wloD, b_hh_enc, b_hh_dec,
                                           gie, gid, Hpk, flags, Hall);

  // logits = h2 @ fc_W^T + fc_b  (M=2048 pad, N=32000, K=512) — 256^2 tile, 8 waves
  constexpr int SMEM_FC = 2 * (256 * 32 * 2) * 2;   // 65536
  static_assert(SMEM_FC == 65536, "unexpected fc LDS size");
  (void)hipFuncSetAttribute(reinterpret_cast<const void*>(&gemm_fc256),
                            hipFuncAttributeMaxDynamicSharedMemorySize, SMEM_FC);
  gemm_fc256<<<1000, 512, SMEM_FC, stream>>>(Hall, fcWbf, fc_b, out, 2016);
}